// Round 8
// baseline (298.611 us; speedup 1.0000x reference)
//
#include <hip/hip_runtime.h>
#include <hip/hip_bf16.h>

typedef __attribute__((ext_vector_type(8))) short short8;
typedef __attribute__((ext_vector_type(4))) short shortx4;
typedef __attribute__((ext_vector_type(4))) float floatx4;
typedef __attribute__((ext_vector_type(4))) unsigned int uintx4;

#define BB 8
#define TT 4096
#define CC 1024
#define HH 128
#define BT (BB * TT)
#define MBASE 16.0f

__device__ __forceinline__ unsigned short f2bf(float f) {
    unsigned int u = __float_as_uint(f);
    u += 0x7fffu + ((u >> 16) & 1u);   // round-to-nearest-even
    return (unsigned short)(u >> 16);
}

// async global->LDS, 16B per lane; lds dest = wave-uniform base + lane*16
__device__ __forceinline__ void async16(const unsigned short* g, unsigned short* l) {
    __builtin_amdgcn_global_load_lds(
        (const __attribute__((address_space(1))) unsigned int*)g,
        (__attribute__((address_space(3))) unsigned int*)l, 16, 0, 0);
}

// ---------------- W [C][H] fp32 (x3) -> Wt [3*H][C] bf16 transposed ----------------
__global__ void conv_w(const float* __restrict__ Wq, const float* __restrict__ Wk,
                       const float* __restrict__ Wv, unsigned short* __restrict__ Wt) {
    __shared__ float tile[32][33];
    const int w = blockIdx.z, nt = blockIdx.y, kt = blockIdx.x;
    const int tx = threadIdx.x, ty = threadIdx.y;  // 32 x 8
    const float* W = (w == 0) ? Wq : ((w == 1) ? Wk : Wv);
#pragma unroll
    for (int i = 0; i < 4; ++i)
        tile[ty + 8 * i][tx] = W[(kt * 32 + ty + 8 * i) * HH + nt * 32 + tx];
    __syncthreads();
#pragma unroll
    for (int i = 0; i < 4; ++i)
        Wt[w * (HH * CC) + (nt * 32 + ty + 8 * i) * CC + kt * 32 + tx] = f2bf(tile[tx][ty + 8 * i]);
}

// ---------------- fused QKV projection v4 (round-6, unchanged) ----------
// BM=128 x BN=192, N-split=2, grid 512, block 512 (8 waves): 2 blocks/CU -> 16 waves/CU.
// Triple-buffered 24 KB B tiles + counted vmcnt; A: fp32 -> regs -> cvt bf16 -> MFMA.
__global__ __launch_bounds__(512, 4) void proj_gemm(
    const float* __restrict__ x, const unsigned short* __restrict__ Wt,
    const float* __restrict__ bq, const float* __restrict__ bk, const float* __restrict__ bv,
    unsigned short* __restrict__ Qb, unsigned short* __restrict__ Kb,
    unsigned short* __restrict__ Vt) {
    __shared__ unsigned short Bs[3][192 * 64];  // swizzled: slot(row,sc) holds chunk sc^(row&7)
    const int gid = blockIdx.x;
    const int c = gid & 7, j = gid >> 3;        // XCD c; siblings (nb=0,1) adjacent on one XCD
    const int mb = c * 32 + (j >> 1);           // 0..255: 128-row slab
    const int nb = j & 1;                       // 0..1: 192-col slice
    const int tid = threadIdx.x, lane = tid & 63, wv = tid >> 6;  // wv 0..7
    const int quad = lane >> 4, l15 = lane & 15;
    const int brow = lane >> 3;                 // staging row-within-group
    const int wc = (lane & 7) ^ (brow & 7);     // swizzled global chunk (loop-invariant)
    const unsigned short* Wp = Wt + (long)nb * 192 * CC;
    const float* xw = x + ((long)mb * 128 + wv * 16 + l15) * CC + quad * 8;
    const int rw = mb * 128 + wv * 16;          // wave's row base (16 rows)

    floatx4 acc[12];
#pragma unroll
    for (int jj = 0; jj < 12; ++jj) {
        floatx4 z = {0.f, 0.f, 0.f, 0.f};
        acc[jj] = z;
    }

    floatx4 pf[4];       // A prefetch regs: static indices only (rule 20)
    short8 af[2];        // current-tile bf16 A-frags (ks = 0,1)

    auto loadA = [&](int kt) {
#pragma unroll
        for (int ks = 0; ks < 2; ++ks) {
            const float* p = xw + kt * 64 + ks * 32;
            pf[ks * 2]     = *(const floatx4*)p;
            pf[ks * 2 + 1] = *(const floatx4*)(p + 4);
        }
    };
    auto cvtA = [&]() {
#pragma unroll
        for (int ks = 0; ks < 2; ++ks) {
            floatx4 a = pf[ks * 2], b2 = pf[ks * 2 + 1];
            short8 r;
            r[0] = (short)f2bf(a[0]);  r[1] = (short)f2bf(a[1]);
            r[2] = (short)f2bf(a[2]);  r[3] = (short)f2bf(a[3]);
            r[4] = (short)f2bf(b2[0]); r[5] = (short)f2bf(b2[1]);
            r[6] = (short)f2bf(b2[2]); r[7] = (short)f2bf(b2[3]);
            af[ks] = r;
        }
    };
    auto stageB = [&](int kt, int buf) {
#pragma unroll
        for (int h = 0; h < 3; ++h) {           // 3 async16 per wave x 8 waves = 24 KB tile
            int grp = 8 * h + wv;               // 0..23
            async16(Wp + (long)(grp * 8 + brow) * CC + kt * 64 + wc * 8, &Bs[buf][grp * 512]);
        }
    };

    // prologue: A(0)x4, B(0)x3, B(1)x3 issued; vmcnt(3) drains A(0)+B(0), leaves B(1)
    loadA(0);
    stageB(0, 0);
    stageB(1, 1);
    __builtin_amdgcn_sched_barrier(0);
    asm volatile("s_waitcnt vmcnt(3)" ::: "memory");
    __builtin_amdgcn_s_barrier();
    __builtin_amdgcn_sched_barrier(0);
    int cur = 0;

    for (int kt = 0; kt < 16; ++kt) {
        cvtA();                                 // waits A(t) precisely (B(t+1) newer, stays)
        if (kt < 15) loadA(kt + 1);
        __builtin_amdgcn_sched_barrier(0);
        if (kt < 14) {                          // stage B(t+2) into the buffer B(t-1) vacated
            int b2 = cur ? cur - 1 : 2;
            stageB(kt + 2, b2);
        }
        __builtin_amdgcn_sched_barrier(0);

        const unsigned short* Bc = Bs[cur];
#pragma unroll
        for (int ks = 0; ks < 2; ++ks)
#pragma unroll
            for (int ni = 0; ni < 12; ++ni) {
                short8 bfr = *(const short8*)&Bc[(ni * 16 + l15) * 64 +
                                                 (((ks * 4 + quad) ^ (l15 & 7)) * 8)];
                acc[ni] = __builtin_amdgcn_mfma_f32_16x16x32_bf16(af[ks], bfr, acc[ni], 0, 0, 0);
            }
        __builtin_amdgcn_sched_barrier(0);

        if (kt < 15) {
            // outstanding (issue order): B(t+1)x3, A(t+1)x4, B(t+2)x3 -> drain only B(t+1)
            if (kt < 14) { asm volatile("s_waitcnt vmcnt(7)" ::: "memory"); }
            else         { asm volatile("s_waitcnt vmcnt(4)" ::: "memory"); }
            __builtin_amdgcn_s_barrier();
            __builtin_amdgcn_sched_barrier(0);
            cur = (cur == 2) ? 0 : cur + 1;
        }
    }

    // epilogue: f = 12*nb + ni: f<8 -> Q (pre-scaled), f<16 -> K, else V (per-wave transpose)
    // kt=15 reads Bs[0] (cur cycles to 0); Bs[1] free as per-wave scratch (last read kt=13).
    const float qscale = 0.08838834764831845f * 1.4426950408889634f;
    unsigned short* Tw = &Bs[1][wv * 768];      // 16 h x 48 (16 t + pad) per wave, 12 KB total
#pragma unroll
    for (int ni = 0; ni < 12; ++ni) {
        int f = 12 * nb + ni;
        int col = f * 16 + l15;
        int h = col & 127;
        if (f < 16) {
            float bval = (f < 8) ? bq[h] : bk[h];
            unsigned short* dst = (f < 8) ? Qb : Kb;
#pragma unroll
            for (int r = 0; r < 4; ++r) {
                int row = rw + quad * 4 + r;
                float v = acc[ni][r] + bval;
                if (f < 8) v *= qscale;
                dst[(long)row * HH + h] = f2bf(v);
            }
        } else {
            float bval = bv[h];
            shortx4 pk;
#pragma unroll
            for (int r = 0; r < 4; ++r) pk[r] = (short)f2bf(acc[ni][r] + bval);
            *(shortx4*)&Tw[l15 * 48 + quad * 4] = pk;   // Tw[h][t]: h=l15, t=quad*4+r
            if (lane < 32) {                    // 16 h x 2 segs of 8 t = 16B stores
                int th = lane >> 1, seg = lane & 1;
                uintx4 q0 = *(const uintx4*)&Tw[th * 48 + seg * 8];
                int hg = (f - 16) * 16 + th;
                int bb = rw >> 12, t0 = (rw & 4095) + seg * 8;
                unsigned short* vp = Vt + (long)bb * (HH * TT) + (long)hg * TT + t0;
                *(uintx4*)vp = q0;
            }
        }
    }
}

// ---------------- flash attention v5: R6 body, split-KV S=2, pair-balanced ----------------
// grid 512 = 8 b (XCD-affine, gid&7) x 32 q-pairs x 2 s; block 512 = 8 waves x 16 q-rows.
// Placement model: block g -> XCD g%8, CU (g/8)%32 -> g and g+256 co-reside on one CU.
// Mapping t<16 -> qp=t else 47-t makes co-resident pairs sum to 66 tiles (constant).
// Compute loop / LDS / staging byte-identical to round 6 (single-buffer 42 KB, async16).
__global__ __launch_bounds__(512, 2) void attn(
    const unsigned short* __restrict__ Qb, const unsigned short* __restrict__ Kb,
    const unsigned short* __restrict__ Vt, unsigned short* __restrict__ Op,
    float* __restrict__ Lh) {
    __shared__ unsigned short Ks[64 * 128];   // swizzled: slot(r,sc) holds chunk sc^(r&15)
    __shared__ unsigned short Vs[128 * 64];   // swizzled: slot(h,sc) holds chunk sc^(h&7)
    __shared__ unsigned short Ps[8 * 16 * 40];
    const int gid = blockIdx.x;
    const int b = gid & 7;                    // XCD affinity: all blocks on XCD share b's KV
    const int idx = gid >> 3;                 // 0..63
    const int s = idx & 1;                    // KV chunk 0/1
    const int t = idx >> 1;                   // 0..31
    const int qp = (t < 16) ? t : 47 - t;     // pair-balanced: co-resident pairs sum to 66 tiles
    const int qb0 = 62 - 2 * qp;              // lower qb of the pair
    const int half = (qb0 + 2) >> 1;          // tiles per s-chunk (len2 always even), >= 1
    const int lo = s * half;
    const int hi = lo + half;
    const int tid = threadIdx.x, lane = tid & 63, wv = tid >> 6;  // wv 0..7
    const int quad = lane >> 4, l15 = lane & 15;
    const int qb_w = qb0 + (wv >> 2);         // this wave's causal diagonal tile
    const int hi_eff = (hi < qb_w + 1) ? hi : qb_w + 1;

    short8 qf[4];
    {
        const unsigned short* qp_ = Qb + ((long)b * TT + qb0 * 64 + wv * 16 + l15) * HH + quad * 8;
#pragma unroll
        for (int ks = 0; ks < 4; ++ks) qf[ks] = *(const short8*)(qp_ + ks * 32);
    }
    floatx4 o[8];
#pragma unroll
    for (int i = 0; i < 8; ++i) {
        floatx4 z = {0.f, 0.f, 0.f, 0.f};
        o[i] = z;
    }
    float l_part[4] = {0.f, 0.f, 0.f, 0.f};

    // staging addresses (loop-invariant components)
    const int kc = l15 ^ ((4 * wv + quad) & 15);
    const unsigned short* Kg = Kb + (long)b * TT * HH + ((long)lo * 64 + 4 * wv + quad) * HH + kc * 8;
    const int vrow = lane >> 3;
    const int vc = (lane & 7) ^ vrow;
    const unsigned short* Vg = Vt + (long)b * HH * TT + (long)(8 * wv + vrow) * TT + lo * 64 + vc * 8;
    unsigned short* Pw = &Ps[wv * 640];

    for (int kb = lo; kb < hi; ++kb) {
#pragma unroll
        for (int h = 0; h < 2; ++h) {         // 2 K + 2 V async16 per wave (8 waves cover tiles)
            int grp = 8 * h + wv;             // 0..15
            async16(Kg + (long)h * 32 * HH, &Ks[grp * 512]);
            async16(Vg + (long)h * 64 * TT, &Vs[grp * 512]);
        }
        Kg += (long)64 * HH;
        Vg += 64;
        __syncthreads();

        if (kb <= qb_w) {                     // wave-uniform causal gate
            floatx4 sArr[4];
#pragma unroll
            for (int nt = 0; nt < 4; ++nt) {
                floatx4 z = {0.f, 0.f, 0.f, 0.f};
                sArr[nt] = z;
            }
            __builtin_amdgcn_s_setprio(1);
#pragma unroll
            for (int ks = 0; ks < 4; ++ks)
#pragma unroll
                for (int nt = 0; nt < 4; ++nt) {
                    short8 kf = *(const short8*)&Ks[(nt * 16 + l15) * 128 + (((ks * 4 + quad) ^ l15) * 8)];
                    sArr[nt] = __builtin_amdgcn_mfma_f32_16x16x32_bf16(qf[ks], kf, sArr[nt], 0, 0, 0);
                }
            __builtin_amdgcn_s_setprio(0);

            if (kb == qb_w) {                 // diagonal causal mask (row within qb_w's 64-block)
                int rowl = (wv & 3) * 16 + quad * 4;
#pragma unroll
                for (int nt = 0; nt < 4; ++nt) {
                    int col = nt * 16 + l15;
#pragma unroll
                    for (int r = 0; r < 4; ++r)
                        if (col > rowl + r) sArr[nt][r] = -1e30f;
                }
            }

            // fixed-base softmax: p = exp2(s - MBASE)
#pragma unroll
            for (int nt = 0; nt < 4; ++nt)
#pragma unroll
                for (int r = 0; r < 4; ++r)
                    sArr[nt][r] = exp2f(sArr[nt][r] - MBASE);
#pragma unroll
            for (int r = 0; r < 4; ++r)
                l_part[r] += (sArr[0][r] + sArr[1][r]) + (sArr[2][r] + sArr[3][r]);

            // PV in two k2 halves through per-wave LDS (C-layout -> A-layout)
#pragma unroll
            for (int k2 = 0; k2 < 2; ++k2) {
#pragma unroll
                for (int ntl = 0; ntl < 2; ++ntl)
#pragma unroll
                    for (int r = 0; r < 4; ++r)
                        Pw[(quad * 4 + r) * 40 + ntl * 16 + l15] = f2bf(sArr[k2 * 2 + ntl][r]);
                short8 pfrag = *(const short8*)&Pw[l15 * 40 + quad * 8];
                __builtin_amdgcn_s_setprio(1);
#pragma unroll
                for (int hn = 0; hn < 8; ++hn) {
                    short8 vf = *(const short8*)&Vs[(hn * 16 + l15) * 64 +
                                                    (((k2 * 4 + quad) ^ (l15 & 7)) * 8)];
                    o[hn] = __builtin_amdgcn_mfma_f32_16x16x32_bf16(pfrag, vf, o[hn], 0, 0, 0);
                }
                __builtin_amdgcn_s_setprio(0);
            }
        }
        __syncthreads();
    }

    long rbase = (long)b * TT + qb0 * 64 + wv * 16 + quad * 4;
    unsigned short* Os = Op + (long)s * BT * HH;
    if (hi_eff > lo) {
#pragma unroll
        for (int hn = 0; hn < 8; ++hn)
#pragma unroll
            for (int r = 0; r < 4; ++r)
                Os[(rbase + r) * HH + hn * 16 + l15] = f2bf(o[hn][r]);
    }
    // reduce l across the 16 l15 lanes (row is fixed per (wv, quad, r))
#pragma unroll
    for (int r = 0; r < 4; ++r) {
        float l = l_part[r];
#pragma unroll
        for (int off = 1; off < 16; off <<= 1) l += __shfl_xor(l, off);
        if (l15 == 0) Lh[(long)s * BT + rbase + r] = (hi_eff > lo) ? l : 0.f;
    }
}

// ---------------- merge the 2 KV-chunk partials: out = (sum o_s) / (sum l_s) ----------------
__global__ __launch_bounds__(256) void merge_kern(
    const unsigned short* __restrict__ Op, const float* __restrict__ Lh,
    float* __restrict__ out) {
    long e = ((long)blockIdx.x * 256 + threadIdx.x) * 8;
    long row = e >> 7;
    float lsum = Lh[row] + Lh[BT + row];
    float inv = 1.f / lsum;
    float acc[8];
#pragma unroll
    for (int j = 0; j < 8; ++j) acc[j] = 0.f;
#pragma unroll
    for (int s = 0; s < 2; ++s) {
        float ls = Lh[(long)s * BT + row];
        if (ls > 0.f) {
            uintx4 p = *(const uintx4*)(Op + (long)s * BT * HH + e);
#pragma unroll
            for (int j = 0; j < 4; ++j) {
                acc[2 * j]     += __uint_as_float(p[j] << 16);
                acc[2 * j + 1] += __uint_as_float(p[j] & 0xffff0000u);
            }
        }
    }
    floatx4 o0, o1;
#pragma unroll
    for (int j = 0; j < 4; ++j) {
        if (j < 2) { o0[2 * j] = acc[2 * j] * inv; o0[2 * j + 1] = acc[2 * j + 1] * inv; }
        else { o1[2 * (j - 2)] = acc[2 * j] * inv; o1[2 * (j - 2) + 1] = acc[2 * j + 1] * inv; }
    }
    *(floatx4*)(out + e) = o0;
    *(floatx4*)(out + e + 4) = o1;
}

extern "C" void kernel_launch(void* const* d_in, const int* in_sizes, int n_in,
                              void* d_out, int out_size, void* d_ws, size_t ws_size,
                              hipStream_t stream) {
    const float* x  = (const float*)d_in[0];
    const float* Wq = (const float*)d_in[1];
    const float* bq = (const float*)d_in[2];
    const float* Wk = (const float*)d_in[3];
    const float* bk = (const float*)d_in[4];
    const float* Wv = (const float*)d_in[5];
    const float* bv = (const float*)d_in[6];
    float* out = (float*)d_out;

    char* ws = (char*)d_ws;
    unsigned short* Wt = (unsigned short*)(ws);               // 786,432 B
    unsigned short* Qb = (unsigned short*)(ws + 1048576);     // pre-scaled by scale*log2e
    unsigned short* Kb = (unsigned short*)(ws + 9437184);
    unsigned short* Vt = (unsigned short*)(ws + 17825792);    // [B][H][T]
    unsigned short* Op = (unsigned short*)(ws + 26214400);    // 2 x 8,388,608 unnormalized partials
    float*          Lh = (float*)(ws + 59768832);             // 2 x 131,072 row sums
    // total ws use: 60,293,120 bytes

    conv_w<<<dim3(32, 4, 3), dim3(32, 8), 0, stream>>>(Wq, Wk, Wv, Wt);
    proj_gemm<<<512, 512, 0, stream>>>(x, Wt, bq, bk, bv, Qb, Kb, Vt);
    attn<<<512, 512, 0, stream>>>(Qb, Kb, Vt, Op, Lh);
    merge_kern<<<2048, 256, 0, stream>>>(Op, Lh, out);
}

// Round 9
// 289.545 us; speedup vs baseline: 1.0313x; 1.0313x over previous
//
#include <hip/hip_runtime.h>
#include <hip/hip_bf16.h>

typedef __attribute__((ext_vector_type(8))) short short8;
typedef __attribute__((ext_vector_type(4))) short shortx4;
typedef __attribute__((ext_vector_type(4))) float floatx4;
typedef __attribute__((ext_vector_type(4))) unsigned int uintx4;

#define BB 8
#define TT 4096
#define CC 1024
#define HH 128
#define BT (BB * TT)
#define MBASE 16.0f

__device__ __forceinline__ unsigned short f2bf(float f) {
    unsigned int u = __float_as_uint(f);
    u += 0x7fffu + ((u >> 16) & 1u);   // round-to-nearest-even
    return (unsigned short)(u >> 16);
}

// async global->LDS, 16B per lane; lds dest = wave-uniform base + lane*16
__device__ __forceinline__ void async16(const unsigned short* g, unsigned short* l) {
    __builtin_amdgcn_global_load_lds(
        (const __attribute__((address_space(1))) unsigned int*)g,
        (__attribute__((address_space(3))) unsigned int*)l, 16, 0, 0);
}

// ---------------- W [C][H] fp32 (x3) -> Wt [3*H][C] bf16 transposed ----------------
__global__ void conv_w(const float* __restrict__ Wq, const float* __restrict__ Wk,
                       const float* __restrict__ Wv, unsigned short* __restrict__ Wt) {
    __shared__ float tile[32][33];
    const int w = blockIdx.z, nt = blockIdx.y, kt = blockIdx.x;
    const int tx = threadIdx.x, ty = threadIdx.y;  // 32 x 8
    const float* W = (w == 0) ? Wq : ((w == 1) ? Wk : Wv);
#pragma unroll
    for (int i = 0; i < 4; ++i)
        tile[ty + 8 * i][tx] = W[(kt * 32 + ty + 8 * i) * HH + nt * 32 + tx];
    __syncthreads();
#pragma unroll
    for (int i = 0; i < 4; ++i)
        Wt[w * (HH * CC) + (nt * 32 + ty + 8 * i) * CC + kt * 32 + tx] = f2bf(tile[tx][ty + 8 * i]);
}

// ---------------- fused QKV projection v4 (round-6, unchanged) ----------
// BM=128 x BN=192, N-split=2, grid 512, block 512 (8 waves): 2 blocks/CU -> 16 waves/CU.
// Triple-buffered 24 KB B tiles + counted vmcnt; A: fp32 -> regs -> cvt bf16 -> MFMA.
__global__ __launch_bounds__(512, 4) void proj_gemm(
    const float* __restrict__ x, const unsigned short* __restrict__ Wt,
    const float* __restrict__ bq, const float* __restrict__ bk, const float* __restrict__ bv,
    unsigned short* __restrict__ Qb, unsigned short* __restrict__ Kb,
    unsigned short* __restrict__ Vt) {
    __shared__ unsigned short Bs[3][192 * 64];  // swizzled: slot(row,sc) holds chunk sc^(row&7)
    const int gid = blockIdx.x;
    const int c = gid & 7, j = gid >> 3;        // XCD c; siblings (nb=0,1) adjacent on one XCD
    const int mb = c * 32 + (j >> 1);           // 0..255: 128-row slab
    const int nb = j & 1;                       // 0..1: 192-col slice
    const int tid = threadIdx.x, lane = tid & 63, wv = tid >> 6;  // wv 0..7
    const int quad = lane >> 4, l15 = lane & 15;
    const int brow = lane >> 3;                 // staging row-within-group
    const int wc = (lane & 7) ^ (brow & 7);     // swizzled global chunk (loop-invariant)
    const unsigned short* Wp = Wt + (long)nb * 192 * CC;
    const float* xw = x + ((long)mb * 128 + wv * 16 + l15) * CC + quad * 8;
    const int rw = mb * 128 + wv * 16;          // wave's row base (16 rows)

    floatx4 acc[12];
#pragma unroll
    for (int jj = 0; jj < 12; ++jj) {
        floatx4 z = {0.f, 0.f, 0.f, 0.f};
        acc[jj] = z;
    }

    floatx4 pf[4];       // A prefetch regs: static indices only (rule 20)
    short8 af[2];        // current-tile bf16 A-frags (ks = 0,1)

    auto loadA = [&](int kt) {
#pragma unroll
        for (int ks = 0; ks < 2; ++ks) {
            const float* p = xw + kt * 64 + ks * 32;
            pf[ks * 2]     = *(const floatx4*)p;
            pf[ks * 2 + 1] = *(const floatx4*)(p + 4);
        }
    };
    auto cvtA = [&]() {
#pragma unroll
        for (int ks = 0; ks < 2; ++ks) {
            floatx4 a = pf[ks * 2], b2 = pf[ks * 2 + 1];
            short8 r;
            r[0] = (short)f2bf(a[0]);  r[1] = (short)f2bf(a[1]);
            r[2] = (short)f2bf(a[2]);  r[3] = (short)f2bf(a[3]);
            r[4] = (short)f2bf(b2[0]); r[5] = (short)f2bf(b2[1]);
            r[6] = (short)f2bf(b2[2]); r[7] = (short)f2bf(b2[3]);
            af[ks] = r;
        }
    };
    auto stageB = [&](int kt, int buf) {
#pragma unroll
        for (int h = 0; h < 3; ++h) {           // 3 async16 per wave x 8 waves = 24 KB tile
            int grp = 8 * h + wv;               // 0..23
            async16(Wp + (long)(grp * 8 + brow) * CC + kt * 64 + wc * 8, &Bs[buf][grp * 512]);
        }
    };

    // prologue: A(0)x4, B(0)x3, B(1)x3 issued; vmcnt(3) drains A(0)+B(0), leaves B(1)
    loadA(0);
    stageB(0, 0);
    stageB(1, 1);
    __builtin_amdgcn_sched_barrier(0);
    asm volatile("s_waitcnt vmcnt(3)" ::: "memory");
    __builtin_amdgcn_s_barrier();
    __builtin_amdgcn_sched_barrier(0);
    int cur = 0;

    for (int kt = 0; kt < 16; ++kt) {
        cvtA();                                 // waits A(t) precisely (B(t+1) newer, stays)
        if (kt < 15) loadA(kt + 1);
        __builtin_amdgcn_sched_barrier(0);
        if (kt < 14) {                          // stage B(t+2) into the buffer B(t-1) vacated
            int b2 = cur ? cur - 1 : 2;
            stageB(kt + 2, b2);
        }
        __builtin_amdgcn_sched_barrier(0);

        const unsigned short* Bc = Bs[cur];
#pragma unroll
        for (int ks = 0; ks < 2; ++ks)
#pragma unroll
            for (int ni = 0; ni < 12; ++ni) {
                short8 bfr = *(const short8*)&Bc[(ni * 16 + l15) * 64 +
                                                 (((ks * 4 + quad) ^ (l15 & 7)) * 8)];
                acc[ni] = __builtin_amdgcn_mfma_f32_16x16x32_bf16(af[ks], bfr, acc[ni], 0, 0, 0);
            }
        __builtin_amdgcn_sched_barrier(0);

        if (kt < 15) {
            // outstanding (issue order): B(t+1)x3, A(t+1)x4, B(t+2)x3 -> drain only B(t+1)
            if (kt < 14) { asm volatile("s_waitcnt vmcnt(7)" ::: "memory"); }
            else         { asm volatile("s_waitcnt vmcnt(4)" ::: "memory"); }
            __builtin_amdgcn_s_barrier();
            __builtin_amdgcn_sched_barrier(0);
            cur = (cur == 2) ? 0 : cur + 1;
        }
    }

    // epilogue: f = 12*nb + ni: f<8 -> Q (pre-scaled), f<16 -> K, else V (per-wave transpose)
    // kt=15 reads Bs[0] (cur cycles to 0); Bs[1] free as per-wave scratch (last read kt=13).
    const float qscale = 0.08838834764831845f * 1.4426950408889634f;
    unsigned short* Tw = &Bs[1][wv * 768];      // 16 h x 48 (16 t + pad) per wave, 12 KB total
#pragma unroll
    for (int ni = 0; ni < 12; ++ni) {
        int f = 12 * nb + ni;
        int col = f * 16 + l15;
        int h = col & 127;
        if (f < 16) {
            float bval = (f < 8) ? bq[h] : bk[h];
            unsigned short* dst = (f < 8) ? Qb : Kb;
#pragma unroll
            for (int r = 0; r < 4; ++r) {
                int row = rw + quad * 4 + r;
                float v = acc[ni][r] + bval;
                if (f < 8) v *= qscale;
                dst[(long)row * HH + h] = f2bf(v);
            }
        } else {
            float bval = bv[h];
            shortx4 pk;
#pragma unroll
            for (int r = 0; r < 4; ++r) pk[r] = (short)f2bf(acc[ni][r] + bval);
            *(shortx4*)&Tw[l15 * 48 + quad * 4] = pk;   // Tw[h][t]: h=l15, t=quad*4+r
            if (lane < 32) {                    // 16 h x 2 segs of 8 t = 16B stores
                int th = lane >> 1, seg = lane & 1;
                uintx4 q0 = *(const uintx4*)&Tw[th * 48 + seg * 8];
                int hg = (f - 16) * 16 + th;
                int bb = rw >> 12, t0 = (rw & 4095) + seg * 8;
                unsigned short* vp = Vt + (long)bb * (HH * TT) + (long)hg * TT + t0;
                *(uintx4*)vp = q0;
            }
        }
    }
}

// ---------------- flash attention v6: R6 decomposition, 2 KV-tiles per barrier epoch -------
// grid 1024 = 8 b (XCD-affine, gid&7) x 32 q-pairs x 4 s; block 512 = 8 waves x 16 q-rows.
// Per epoch: stage K/V for tiles kb and kb+1 into two LDS halves (74 KB), ONE barrier pair,
// compute both sub-tiles back-to-back. Halves barrier count + staging drains per tile.
// Per-tile compute body identical to round 6; per-sub causal gate/mask.
__global__ __launch_bounds__(512, 2) void attn(
    const unsigned short* __restrict__ Qb, const unsigned short* __restrict__ Kb,
    const unsigned short* __restrict__ Vt, unsigned short* __restrict__ Op,
    float* __restrict__ Lh) {
    __shared__ unsigned short Ks[2][64 * 128];   // half 'sub': swizzled slot(r,sc) = chunk sc^(r&15)
    __shared__ unsigned short Vs[2][128 * 64];   // half 'sub': swizzled slot(h,sc) = chunk sc^(h&7)
    __shared__ unsigned short Ps[8 * 16 * 40];
    const int gid = blockIdx.x;
    const int b = gid & 7;                    // XCD affinity: all blocks on XCD share b's KV
    const int idx = gid >> 3;                 // 0..127
    const int qp = idx >> 2;                  // 0..31, ascending -> qb0 descending (big first)
    const int s = idx & 3;                    // 0..3 KV chunk
    const int qb0 = 62 - 2 * qp;              // lower qb of the pair
    const int len2 = qb0 + 2;                 // tiles in union causal range
    const int lo = (s * len2) >> 2;
    const int hi = ((s + 1) * len2) >> 2;
    const int tid = threadIdx.x, lane = tid & 63, wv = tid >> 6;  // wv 0..7
    const int quad = lane >> 4, l15 = lane & 15;
    const int qb_w = qb0 + (wv >> 2);         // this wave's causal diagonal tile
    const int hi_eff = (hi < qb_w + 1) ? hi : qb_w + 1;

    short8 qf[4];
    {
        const unsigned short* qp_ = Qb + ((long)b * TT + qb0 * 64 + wv * 16 + l15) * HH + quad * 8;
#pragma unroll
        for (int ks = 0; ks < 4; ++ks) qf[ks] = *(const short8*)(qp_ + ks * 32);
    }
    floatx4 o[8];
#pragma unroll
    for (int i = 0; i < 8; ++i) {
        floatx4 z = {0.f, 0.f, 0.f, 0.f};
        o[i] = z;
    }
    float l_part[4] = {0.f, 0.f, 0.f, 0.f};

    // staging addresses (loop-invariant components)
    const int kc = l15 ^ ((4 * wv + quad) & 15);
    const unsigned short* Kg = Kb + (long)b * TT * HH + ((long)lo * 64 + 4 * wv + quad) * HH + kc * 8;
    const int vrow = lane >> 3;
    const int vc = (lane & 7) ^ vrow;
    const unsigned short* Vg = Vt + (long)b * HH * TT + (long)(8 * wv + vrow) * TT + lo * 64 + vc * 8;
    unsigned short* Pw = &Ps[wv * 640];

    for (int kb = lo; kb < hi; kb += 2) {
        const bool two = (kb + 1 < hi);
        // stage tile kb -> half 0 (and kb+1 -> half 1 when present)
#pragma unroll
        for (int h = 0; h < 2; ++h) {         // 2 K + 2 V async16 per wave per half
            int grp = 8 * h + wv;             // 0..15
            async16(Kg + (long)h * 32 * HH, &Ks[0][grp * 512]);
            async16(Vg + (long)h * 64 * TT, &Vs[0][grp * 512]);
        }
        if (two) {
#pragma unroll
            for (int h = 0; h < 2; ++h) {
                int grp = 8 * h + wv;
                async16(Kg + (long)64 * HH + (long)h * 32 * HH, &Ks[1][grp * 512]);
                async16(Vg + 64 + (long)h * 64 * TT, &Vs[1][grp * 512]);
            }
        }
        Kg += (long)128 * HH;
        Vg += 128;
        __syncthreads();

#pragma unroll
        for (int sub = 0; sub < 2; ++sub) {
            if (sub == 1 && !two) break;
            const int kbs = kb + sub;
            if (kbs <= qb_w) {                // wave-uniform causal gate (no barriers inside)
                const unsigned short* Kc = Ks[sub];
                const unsigned short* Vc = Vs[sub];
                floatx4 sArr[4];
#pragma unroll
                for (int nt = 0; nt < 4; ++nt) {
                    floatx4 z = {0.f, 0.f, 0.f, 0.f};
                    sArr[nt] = z;
                }
                __builtin_amdgcn_s_setprio(1);
#pragma unroll
                for (int ks = 0; ks < 4; ++ks)
#pragma unroll
                    for (int nt = 0; nt < 4; ++nt) {
                        short8 kf = *(const short8*)&Kc[(nt * 16 + l15) * 128 + (((ks * 4 + quad) ^ l15) * 8)];
                        sArr[nt] = __builtin_amdgcn_mfma_f32_16x16x32_bf16(qf[ks], kf, sArr[nt], 0, 0, 0);
                    }
                __builtin_amdgcn_s_setprio(0);

                if (kbs == qb_w) {            // diagonal causal mask (row within qb_w's 64-block)
                    int rowl = (wv & 3) * 16 + quad * 4;
#pragma unroll
                    for (int nt = 0; nt < 4; ++nt) {
                        int col = nt * 16 + l15;
#pragma unroll
                        for (int r = 0; r < 4; ++r)
                            if (col > rowl + r) sArr[nt][r] = -1e30f;
                    }
                }

                // fixed-base softmax: p = exp2(s - MBASE)
#pragma unroll
                for (int nt = 0; nt < 4; ++nt)
#pragma unroll
                    for (int r = 0; r < 4; ++r)
                        sArr[nt][r] = exp2f(sArr[nt][r] - MBASE);
#pragma unroll
                for (int r = 0; r < 4; ++r)
                    l_part[r] += (sArr[0][r] + sArr[1][r]) + (sArr[2][r] + sArr[3][r]);

                // PV in two k2 halves through per-wave LDS (C-layout -> A-layout)
#pragma unroll
                for (int k2 = 0; k2 < 2; ++k2) {
#pragma unroll
                    for (int ntl = 0; ntl < 2; ++ntl)
#pragma unroll
                        for (int r = 0; r < 4; ++r)
                            Pw[(quad * 4 + r) * 40 + ntl * 16 + l15] = f2bf(sArr[k2 * 2 + ntl][r]);
                    short8 pfrag = *(const short8*)&Pw[l15 * 40 + quad * 8];
                    __builtin_amdgcn_s_setprio(1);
#pragma unroll
                    for (int hn = 0; hn < 8; ++hn) {
                        short8 vf = *(const short8*)&Vc[(hn * 16 + l15) * 64 +
                                                        (((k2 * 4 + quad) ^ (l15 & 7)) * 8)];
                        o[hn] = __builtin_amdgcn_mfma_f32_16x16x32_bf16(pfrag, vf, o[hn], 0, 0, 0);
                    }
                    __builtin_amdgcn_s_setprio(0);
                }
            }
        }
        __syncthreads();
    }

    long rbase = (long)b * TT + qb0 * 64 + wv * 16 + quad * 4;
    unsigned short* Os = Op + (long)s * BT * HH;
    if (hi_eff > lo) {
#pragma unroll
        for (int hn = 0; hn < 8; ++hn)
#pragma unroll
            for (int r = 0; r < 4; ++r)
                Os[(rbase + r) * HH + hn * 16 + l15] = f2bf(o[hn][r]);
    }
    // reduce l across the 16 l15 lanes (row is fixed per (wv, quad, r))
#pragma unroll
    for (int r = 0; r < 4; ++r) {
        float l = l_part[r];
#pragma unroll
        for (int off = 1; off < 16; off <<= 1) l += __shfl_xor(l, off);
        if (l15 == 0) Lh[(long)s * BT + rbase + r] = (hi_eff > lo) ? l : 0.f;
    }
}

// ---------------- merge the 4 KV-chunk partials: out = (sum o_s) / (sum l_s) ----------------
__global__ __launch_bounds__(256) void merge_kern(
    const unsigned short* __restrict__ Op, const float* __restrict__ Lh,
    float* __restrict__ out) {
    long e = ((long)blockIdx.x * 256 + threadIdx.x) * 8;
    long row = e >> 7;
    float lsum = Lh[row] + Lh[BT + row] + Lh[2 * (long)BT + row] + Lh[3 * (long)BT + row];
    float inv = 1.f / lsum;
    float acc[8];
#pragma unroll
    for (int j = 0; j < 8; ++j) acc[j] = 0.f;
#pragma unroll
    for (int s = 0; s < 4; ++s) {
        float ls = Lh[(long)s * BT + row];
        if (ls > 0.f) {
            uintx4 p = *(const uintx4*)(Op + (long)s * BT * HH + e);
#pragma unroll
            for (int j = 0; j < 4; ++j) {
                acc[2 * j]     += __uint_as_float(p[j] << 16);
                acc[2 * j + 1] += __uint_as_float(p[j] & 0xffff0000u);
            }
        }
    }
    floatx4 o0, o1;
#pragma unroll
    for (int j = 0; j < 4; ++j) {
        if (j < 2) { o0[2 * j] = acc[2 * j] * inv; o0[2 * j + 1] = acc[2 * j + 1] * inv; }
        else { o1[2 * (j - 2)] = acc[2 * j] * inv; o1[2 * (j - 2) + 1] = acc[2 * j + 1] * inv; }
    }
    *(floatx4*)(out + e) = o0;
    *(floatx4*)(out + e + 4) = o1;
}

extern "C" void kernel_launch(void* const* d_in, const int* in_sizes, int n_in,
                              void* d_out, int out_size, void* d_ws, size_t ws_size,
                              hipStream_t stream) {
    const float* x  = (const float*)d_in[0];
    const float* Wq = (const float*)d_in[1];
    const float* bq = (const float*)d_in[2];
    const float* Wk = (const float*)d_in[3];
    const float* bk = (const float*)d_in[4];
    const float* Wv = (const float*)d_in[5];
    const float* bv = (const float*)d_in[6];
    float* out = (float*)d_out;

    char* ws = (char*)d_ws;
    unsigned short* Wt = (unsigned short*)(ws);               // 786,432 B
    unsigned short* Qb = (unsigned short*)(ws + 1048576);     // pre-scaled by scale*log2e
    unsigned short* Kb = (unsigned short*)(ws + 9437184);
    unsigned short* Vt = (unsigned short*)(ws + 17825792);    // [B][H][T]
    unsigned short* Op = (unsigned short*)(ws + 26214400);    // 4 x 8,388,608 unnormalized partials
    float*          Lh = (float*)(ws + 59768832);             // 4 x 131,072 row sums
    // total ws use: 60,293,120 bytes

    conv_w<<<dim3(32, 4, 3), dim3(32, 8), 0, stream>>>(Wq, Wk, Wv, Wt);
    proj_gemm<<<512, 512, 0, stream>>>(x, Wt, bq, bk, bv, Qb, Kb, Vt);
    attn<<<1024, 512, 0, stream>>>(Qb, Kb, Vt, Op, Lh);
    merge_kern<<<2048, 256, 0, stream>>>(Op, Lh, out);
}